// Round 3
// baseline (67.068 us; speedup 1.0000x reference)
//
#include <hip/hip_runtime.h>
#include <hip/hip_bf16.h>

// Problem: B=512, S=256, E=384, H=64.
// d_in: x [B,S,E] f32; Wq,Wk,Wv [E,H] f32.  d_out: [B,S,H] f32.
// ws: [0, 262144) wfrag bf16 (only region used).
//
// FUSED v3: one block per batch, 256 threads (4 waves), LDS exactly 80 KB
// -> 2 blocks/CU co-resident: block B's projection HBM loads overlap block
// A's (HBM-idle) attention phase. P never touches LDS: swapped-operand
// scores + interleaved k-tiling make the PV A-fragment assembly fully
// in-lane (cvt_pk only). Q transits a 4 KB 2-slot ring; 2-pass softmax
// (recompute) removes the s[16] register array.

#define NB   512
#define SS   256
#define EE   384
#define HH   64

typedef short bf16x8 __attribute__((ext_vector_type(8)));
typedef float f32x4  __attribute__((ext_vector_type(4)));

__device__ __forceinline__ short f2bf(float f) {
  union { float f; unsigned u; } x; x.f = f;
  unsigned r = x.u + 0x7fffu + ((x.u >> 16) & 1u);
  return (short)(r >> 16);
}

// ---------------- prep: W -> fragment-ordered bf16 (unchanged) ----------------
// wfrag[((ks*12+nf)*64 + lane)*8 + j] = Wcat[ks*32 + (lane>>4)*8 + j][nf*16 + (lane&15)]
__global__ __launch_bounds__(256) void prep_w_kernel(
    const float* __restrict__ Wq, const float* __restrict__ Wk,
    const float* __restrict__ Wv, short* __restrict__ wfrag) {
  int t = blockIdx.x * 256 + threadIdx.x;
  if (t >= 12 * 12 * 64) return;
  int ks  = t / (12 * 64);
  int rem = t % (12 * 64);
  int nf  = rem / 64;
  int l   = rem % 64;
  int l15 = l & 15, lhi = l >> 4;
  int ncat = nf * 16 + l15;
  const float* W = (ncat < 64) ? Wq : (ncat < 128 ? Wk : Wv);
  int n = ncat & 63;
  short* dst = wfrag + (size_t)t * 8;
#pragma unroll
  for (int j = 0; j < 8; ++j) {
    int kk = ks * 32 + lhi * 8 + j;
    dst[j] = f2bf(W[kk * 64 + n]);
  }
}

// ---------------- fused: one block = one batch, 4 waves, 80 KB LDS ----------------
__global__ __launch_bounds__(256, 2) void fused_kernel(
    const float* __restrict__ x, const short* __restrict__ wfrag,
    float* __restrict__ out) {
  // K swizzled: elem (row,h) at Kl[row*64 + (h ^ (s(row)<<3))], s(row)=((row&8)>>1)|(row&3)
  // V^T swizzled: elem (h,row) at Vt[h*256 + (row ^ ((h&7)<<3))]
  // x stage: row-major 16x384 bf16, 16B-chunk c16 stored at (c16 ^ (row&7))
  // ring: 2 slots of Q row-tile [16][64], col ^ ((row&7)<<3)
  __shared__ __align__(16) short Kl[SS * HH];        // 32 KB
  __shared__ __align__(16) short Vt[HH * SS];        // 32 KB
  __shared__ __align__(16) short xst[16 * EE];       // 12 KB
  __shared__ __align__(16) short ring[2 * 16 * 64];  //  4 KB  -> 80 KB total

  int b    = blockIdx.x;
  int tid  = threadIdx.x;
  int lane = tid & 63, wv = tid >> 6;
  int l15  = lane & 15, lhi = lane >> 4;
  int sw   = l15 & 7;
  const float* xb = x + (size_t)b * SS * EE;

  // ---- W fragments resident (3 per wave: f = wv*3+ht), 36 x bf16x8 = 144 VGPR ----
  bf16x8 af[12][3];
#pragma unroll
  for (int ks = 0; ks < 12; ++ks)
#pragma unroll
    for (int h = 0; h < 3; ++h)
      af[ks][h] = *(const bf16x8*)(wfrag + ((size_t)(ks * 12 + wv * 3 + h) * 64 + lane) * 8);

  f32x4 st[6];
  auto loadch = [&](int ch) {  // 16 rows = 24 KB f32, fully contiguous
    const float* p0 = xb + (size_t)ch * 16 * EE;
#pragma unroll
    for (int i = 0; i < 3; ++i) {
      const f32x4* p = (const f32x4*)(p0 + (size_t)(tid + 256 * i) * 8);
      st[2 * i]     = p[0];
      st[2 * i + 1] = p[1];
    }
  };
  auto writech = [&]() {  // regs -> bf16 -> swizzled LDS tile
#pragma unroll
    for (int i = 0; i < 3; ++i) {
      int c = tid + 256 * i;          // 8-float group: row = c/48, cg = c%48
      int row = c / 48, cg = c % 48;
      union { bf16x8 vv; __hip_bfloat162 h2[4]; } u;
      u.h2[0] = __float22bfloat162_rn(make_float2(st[2*i][0],   st[2*i][1]));
      u.h2[1] = __float22bfloat162_rn(make_float2(st[2*i][2],   st[2*i][3]));
      u.h2[2] = __float22bfloat162_rn(make_float2(st[2*i+1][0], st[2*i+1][1]));
      u.h2[3] = __float22bfloat162_rn(make_float2(st[2*i+1][2], st[2*i+1][3]));
      *(bf16x8*)(xst + row * 384 + ((cg ^ (row & 7)) * 8)) = u.vv;
    }
  };

  bf16x8 qa[4][2];   // Q A/B-fragments for this wave's 4 tiles {wv,7-wv,8+wv,15-wv}

  // ---- projection: 16 chunks of 16 rows, single-buffered, Q via ring ----
  loadch(0);
  writech();
  for (int ch = 0; ch < 16; ++ch) {
    __syncthreads();                    // A: xst(ch) + ring(ch-1) visible

    if (ch >= 1) {                      // hoist Q of row-tile ch-1 (owner wave only)
      int rtp = ch - 1;
      const short* slot = ring + (rtp & 1) * 1024;
#pragma unroll
      for (int uu = 0; uu < 4; ++uu) {
        int rtu = (uu == 0) ? wv : (uu == 1) ? (7 - wv) : (uu == 2) ? (8 + wv) : (15 - wv);
        if (rtp == rtu) {
#pragma unroll
          for (int kf = 0; kf < 2; ++kf)
            qa[uu][kf] = *(const bf16x8*)(slot + l15 * 64 + ((kf * 32 + lhi * 8) ^ (sw << 3)));
        }
      }
    }

    if (ch < 15) loadch(ch + 1);        // issue next chunk's global loads

    f32x4 acc[3];
#pragma unroll
    for (int h = 0; h < 3; ++h) acc[h] = (f32x4){0.f, 0.f, 0.f, 0.f};
#pragma unroll
    for (int ks = 0; ks < 12; ++ks) {
      bf16x8 bx = *(const bf16x8*)(xst + l15 * 384 + (((ks * 4 + lhi) ^ sw) * 8));
#pragma unroll
      for (int h = 0; h < 3; ++h)
        acc[h] = __builtin_amdgcn_mfma_f32_16x16x32_bf16(af[ks][h], bx, acc[h], 0, 0, 0);
    }

    // epilogue: f = wv*3+ht, ncat = f*16+lhi*4; row = ch*16+l15
    int row  = ch * 16 + l15;
    int srow = ((row & 8) >> 1) | (row & 3);
#pragma unroll
    for (int ht = 0; ht < 3; ++ht) {
      int f = wv * 3 + ht;
      int ncat = f * 16 + lhi * 4;
      if (f < 8) {
        union { short4 s4; __hip_bfloat162 h2[2]; } o;
        o.h2[0] = __float22bfloat162_rn(make_float2(acc[ht][0], acc[ht][1]));
        o.h2[1] = __float22bfloat162_rn(make_float2(acc[ht][2], acc[ht][3]));
        if (f < 4) {   // Q -> ring slot (row in ring = l15)
          *(short4*)(ring + (ch & 1) * 1024 + l15 * 64 + (ncat ^ (sw << 3))) = o.s4;
        } else {       // K -> Kl, new s(row) swizzle
          int col = ncat - 64;
          *(short4*)(Kl + row * 64 + (col ^ (srow << 3))) = o.s4;
        }
      } else {         // V -> Vt transposed, scalar stores
#pragma unroll
        for (int j = 0; j < 4; ++j) {
          int h = ncat - 128 + j;
          Vt[h * 256 + (row ^ ((h & 7) << 3))] = f2bf(acc[ht][j]);
        }
      }
    }
    __syncthreads();                    // B: all reads of xst(ch) done
    if (ch < 15) writech();             // overwrite stage with chunk ch+1
  }
  __syncthreads();                      // Kl/Vt complete; ring slot 1 = tile 15
  {
    const short* slot = ring + 1024;    // rtp = 15
#pragma unroll
    for (int uu = 0; uu < 4; ++uu) {
      int rtu = (uu == 0) ? wv : (uu == 1) ? (7 - wv) : (uu == 2) ? (8 + wv) : (15 - wv);
      if (rtu == 15) {
#pragma unroll
        for (int kf = 0; kf < 2; ++kf)
          qa[uu][kf] = *(const bf16x8*)(slot + l15 * 64 + ((kf * 32 + lhi * 8) ^ (sw << 3)));
      }
    }
  }

  // ---- attention: per wave 4 tiles, swapped scores, in-lane P, 2-pass softmax ----
  size_t obase = (size_t)b * SS * HH;
#pragma unroll
  for (int u = 0; u < 4; ++u) {
    int rt = (u == 0) ? wv : (u == 1) ? (7 - wv) : (u == 2) ? (8 + wv) : (15 - wv);
    int qrow0 = rt * 16;
    int twp = (rt + 2) & ~1;            // even # of interleaved 16-row k-tiles
    int nk  = twp >> 1;                 // 32-k PV chunks
    int qg  = qrow0 + l15;              // this lane's q-row (P lives at q=l15)

    // pass 1: row max. tile t loads K rows kc = (t>>1)*32 + (l15>>2)*8 + (t&1)*4 + (l15&3)
    float mx = -3.0e38f;
    for (int t = 0; t < twp; ++t) {
      int kc = (t >> 1) * 32 + ((l15 >> 2) << 3) + ((t & 1) << 2) + (l15 & 3);
      const short* kp = Kl + kc * 64;
      bf16x8 kb0 = *(const bf16x8*)(kp + ((lhi * 8) ^ (sw << 3)));
      bf16x8 kb1 = *(const bf16x8*)(kp + ((32 + lhi * 8) ^ (sw << 3)));
      f32x4 a = (f32x4){0.f, 0.f, 0.f, 0.f};
      a = __builtin_amdgcn_mfma_f32_16x16x32_bf16(kb0, qa[u][0], a, 0, 0, 0);
      a = __builtin_amdgcn_mfma_f32_16x16x32_bf16(kb1, qa[u][1], a, 0, 0, 0);
#pragma unroll
      for (int r = 0; r < 4; ++r) {
        int kg = (t >> 1) * 32 + lhi * 8 + ((t & 1) << 2) + r;
        float v = a[r] * 0.125f;
        mx = (kg <= qg) ? fmaxf(mx, v) : mx;
      }
    }
    mx = fmaxf(mx, __shfl_xor(mx, 16));
    mx = fmaxf(mx, __shfl_xor(mx, 32));

    // pass 2: recompute scores, exp, accumulate sum, in-lane pa, PV
    float sm = 0.f;
    f32x4 o[4];
#pragma unroll
    for (int nf = 0; nf < 4; ++nf) o[nf] = (f32x4){0.f, 0.f, 0.f, 0.f};
    for (int kc2 = 0; kc2 < nk; ++kc2) {
      int kcA = kc2 * 32 + ((l15 >> 2) << 3) + (l15 & 3);
      const short* kpA = Kl + kcA * 64;
      const short* kpB = kpA + 4 * 64;
      bf16x8 a0 = *(const bf16x8*)(kpA + ((lhi * 8) ^ (sw << 3)));
      bf16x8 a1 = *(const bf16x8*)(kpA + ((32 + lhi * 8) ^ (sw << 3)));
      bf16x8 b0 = *(const bf16x8*)(kpB + ((lhi * 8) ^ (sw << 3)));
      bf16x8 b1 = *(const bf16x8*)(kpB + ((32 + lhi * 8) ^ (sw << 3)));
      f32x4 aA = (f32x4){0.f, 0.f, 0.f, 0.f};
      aA = __builtin_amdgcn_mfma_f32_16x16x32_bf16(a0, qa[u][0], aA, 0, 0, 0);
      aA = __builtin_amdgcn_mfma_f32_16x16x32_bf16(a1, qa[u][1], aA, 0, 0, 0);
      f32x4 aB = (f32x4){0.f, 0.f, 0.f, 0.f};
      aB = __builtin_amdgcn_mfma_f32_16x16x32_bf16(b0, qa[u][0], aB, 0, 0, 0);
      aB = __builtin_amdgcn_mfma_f32_16x16x32_bf16(b1, qa[u][1], aB, 0, 0, 0);
      float pA[4], pB[4];
#pragma unroll
      for (int r = 0; r < 4; ++r) {
        int kgA = kc2 * 32 + lhi * 8 + r;
        pA[r] = (kgA <= qg) ? __expf(aA[r] * 0.125f - mx) : 0.f;
        pB[r] = (kgA + 4 <= qg) ? __expf(aB[r] * 0.125f - mx) : 0.f;
        sm += pA[r] + pB[r];
      }
      union { bf16x8 v; __hip_bfloat162 h2[4]; } pu;
      pu.h2[0] = __float22bfloat162_rn(make_float2(pA[0], pA[1]));
      pu.h2[1] = __float22bfloat162_rn(make_float2(pA[2], pA[3]));
      pu.h2[2] = __float22bfloat162_rn(make_float2(pB[0], pB[1]));
      pu.h2[3] = __float22bfloat162_rn(make_float2(pB[2], pB[3]));
      int kofs = kc2 * 32 + lhi * 8;
#pragma unroll
      for (int nf = 0; nf < 4; ++nf) {
        int hrow = nf * 16 + l15;
        bf16x8 vb = *(const bf16x8*)(Vt + hrow * 256 + (kofs ^ ((hrow & 7) << 3)));
        o[nf] = __builtin_amdgcn_mfma_f32_16x16x32_bf16(pu.v, vb, o[nf], 0, 0, 0);
      }
    }
    sm += __shfl_xor(sm, 16);
    sm += __shfl_xor(sm, 32);
    float inv = 1.f / sm;
    float invq[4];
#pragma unroll
    for (int r = 0; r < 4; ++r) invq[r] = __shfl(inv, lhi * 4 + r);

#pragma unroll
    for (int nf = 0; nf < 4; ++nf)
#pragma unroll
      for (int r = 0; r < 4; ++r) {
        int q = qrow0 + lhi * 4 + r;
        int h = nf * 16 + l15;
        out[obase + (size_t)q * HH + h] = o[nf][r] * invq[r];
      }
  }
}

extern "C" void kernel_launch(void* const* d_in, const int* in_sizes, int n_in,
                              void* d_out, int out_size, void* d_ws, size_t ws_size,
                              hipStream_t stream) {
  const float* x  = (const float*)d_in[0];
  const float* Wq = (const float*)d_in[1];
  const float* Wk = (const float*)d_in[2];
  const float* Wv = (const float*)d_in[3];
  float* out = (float*)d_out;

  short* wfrag = (short*)d_ws;

  prep_w_kernel<<<36, 256, 0, stream>>>(Wq, Wk, Wv, wfrag);
  fused_kernel<<<512, 256, 0, stream>>>(x, wfrag, out);
}